// Round 6
// baseline (159.370 us; speedup 1.0000x reference)
//
#include <hip/hip_runtime.h>

#define BB 2
#define SDIM 1024
#define DDIM 128
#define K1_ROWS 4

#define F4GET(v,k) ((k)==0?(v).x:((k)==1?(v).y:((k)==2?(v).z:(v).w)))

typedef float f2 __attribute__((ext_vector_type(2)));

// ---------------- Kernel 1: projections + row dot products ----------------
// (unchanged from R5 for attribution)
__global__ __launch_bounds__(256) void proj_kernel(
    const float* __restrict__ x, const float* __restrict__ W1,
    const float* __restrict__ b1, const float* __restrict__ W2,
    const float* __restrict__ b2,
    float* __restrict__ hi, float* __restrict__ hjb,
    float* __restrict__ si2, float* __restrict__ sj2, float* __restrict__ w2h)
{
    __shared__ float sX[K1_ROWS][DDIM];
    __shared__ float sRed[4][K1_ROWS];
    const int tid  = threadIdx.x;
    const int d    = tid & 127;
    const int half = tid >> 7;
    const int r0   = blockIdx.x * K1_ROWS;

    if (tid < K1_ROWS * DDIM / 4) {
        reinterpret_cast<float4*>(&sX[0][0])[tid] =
            reinterpret_cast<const float4*>(x + (size_t)r0 * DDIM)[tid];
    }
    __syncthreads();

    const float* Wh = W1 + (size_t)half * DDIM * DDIM;

    float acc[K1_ROWS];
    #pragma unroll
    for (int r = 0; r < K1_ROWS; ++r) acc[r] = 0.f;

    #pragma unroll 4
    for (int k = 0; k < DDIM; k += 4) {
        float4 xv[K1_ROWS];
        #pragma unroll
        for (int r = 0; r < K1_ROWS; ++r)
            xv[r] = *reinterpret_cast<const float4*>(&sX[r][k]);
        #pragma unroll
        for (int kk = 0; kk < 4; ++kk) {
            float w = Wh[(size_t)(k + kk) * DDIM + d];
            #pragma unroll
            for (int r = 0; r < K1_ROWS; ++r)
                acc[r] = fmaf(F4GET(xv[r], kk), w, acc[r]);
        }
    }

    if (half) {
        const float bv = b1[d];
        #pragma unroll
        for (int r = 0; r < K1_ROWS; ++r) acc[r] += bv;
    }

    float* hout = half ? hjb : hi;
    #pragma unroll
    for (int r = 0; r < K1_ROWS; ++r)
        hout[(size_t)(r0 + r) * DDIM + d] = acc[r];

    const float wv = W2[d];
    if (!half) w2h[d] = 0.5f * wv;   // idempotent across blocks
    const int lane = tid & 63;
    const int wave = tid >> 6;
    #pragma unroll
    for (int r = 0; r < K1_ROWS; ++r) {
        float v = acc[r] * wv;
        #pragma unroll
        for (int off = 32; off >= 1; off >>= 1)
            v += __shfl_xor(v, off, 64);
        if (lane == 0) sRed[wave][r] = v;
    }
    __syncthreads();
    if (tid < K1_ROWS) {
        si2[r0 + tid] = 0.5f * (sRed[0][tid] + sRed[1][tid]);
    } else if (tid < 2 * K1_ROWS) {
        int r = tid - K1_ROWS;
        sj2[r0 + r] = 0.5f * (sRed[2][r] + sRed[3][r]) + b2[0];
    }
}

// ---------------- Kernel 2: pairwise edge logits ----------------
// out[b,i,j] = si2[b,i] + sj2[b,j] + sum_d |hi[b,i,d] + hjb[b,j,d]| * w2h[d]
// Block: 64 i-rows x 32 j-cols. A tile (64x128) in LDS, swizzled; lane -> i-row.
// Per 32-d chunk: lane's A-chunk in 32 VGPRs (read once, reused over 8 j).
// B rows + W wave-uniform -> scalar loads (SGPR, scalar pipe). One barrier.
__global__ __launch_bounds__(256, 4) void edge_kernel(
    const float* __restrict__ hi, const float* __restrict__ hjb,
    const float* __restrict__ si2, const float* __restrict__ sj2,
    const float* __restrict__ w2h, float* __restrict__ out)
{
    __shared__ float sA[64 * DDIM];   // 32 KB, f4-quad swizzled

    const int tid  = threadIdx.x;
    const int lane = tid & 63;
    const int w    = __builtin_amdgcn_readfirstlane(tid >> 6);  // wave 0..3
    const int jg   = blockIdx.x;      // 0..31  (32 j per block)
    const int ig   = blockIdx.y;      // 0..15  (64 i per block)
    const int bz   = blockIdx.z;

    const int rowg = bz * SDIM + ig * 64;   // flat hi row base

    // Stage A: coalesced global read -> swizzled LDS write (conflict-free).
    {
        const float4* src = reinterpret_cast<const float4*>(hi + (size_t)rowg * DDIM);
        float4* dst = reinterpret_cast<float4*>(sA);
        #pragma unroll
        for (int k = 0; k < 8; ++k) {
            int idx = k * 256 + tid;              // 0..2047
            int row = idx >> 5, qf = idx & 31;
            dst[row * 32 + (qf ^ (row & 31))] = src[idx];
        }
    }
    __syncthreads();

    const int jbase = bz * SDIM + jg * 32 + w * 8;  // flat hjb row, jj=0
    const float si  = si2[rowg + lane];

    // Two accumulators per j (chain depth 16) -> 16 VGPR.
    float acc0[8], acc1[8];
    #pragma unroll
    for (int jj = 0; jj < 8; ++jj) { acc0[jj] = 0.f; acc1[jj] = 0.f; }

    const float4* sAf = reinterpret_cast<const float4*>(sA);
    const float4* Wp  = reinterpret_cast<const float4*>(w2h);

    #pragma unroll
    for (int c = 0; c < 4; ++c) {
        // Lane's A chunk: 8 x ds_read_b128, conflict-free via XOR swizzle.
        float4 A[8];
        #pragma unroll
        for (int q = 0; q < 8; ++q)
            A[q] = sAf[lane * 32 + ((c * 8 + q) ^ (lane & 31))];

        #pragma unroll
        for (int jj = 0; jj < 8; ++jj) {
            // Wave-uniform B row chunk -> scalar loads.
            const float4* Bp = reinterpret_cast<const float4*>(
                hjb + (size_t)(jbase + jj) * DDIM) + c * 8;
            float a0 = acc0[jj], a1 = acc1[jj];
            #pragma unroll
            for (int q = 0; q < 8; q += 2) {
                const float4 Av0 = A[q],     Bv0 = Bp[q],     Wv0 = Wp[c * 8 + q];
                const float4 Av1 = A[q + 1], Bv1 = Bp[q + 1], Wv1 = Wp[c * 8 + q + 1];
                f2 s01 = (f2){Av0.x, Av0.y} + (f2){Bv0.x, Bv0.y};
                f2 s23 = (f2){Av0.z, Av0.w} + (f2){Bv0.z, Bv0.w};
                f2 u01 = (f2){Av1.x, Av1.y} + (f2){Bv1.x, Bv1.y};
                f2 u23 = (f2){Av1.z, Av1.w} + (f2){Bv1.z, Bv1.w};
                a0 = fmaf(fabsf(s01.x), Wv0.x, a0);
                a1 = fmaf(fabsf(s01.y), Wv0.y, a1);
                a0 = fmaf(fabsf(s23.x), Wv0.z, a0);
                a1 = fmaf(fabsf(s23.y), Wv0.w, a1);
                a0 = fmaf(fabsf(u01.x), Wv1.x, a0);
                a1 = fmaf(fabsf(u01.y), Wv1.y, a1);
                a0 = fmaf(fabsf(u23.x), Wv1.z, a0);
                a1 = fmaf(fabsf(u23.y), Wv1.w, a1);
            }
            acc0[jj] = a0; acc1[jj] = a1;
        }
    }

    // Epilogue: 8 consecutive j per lane -> 2 float4 stores.
    const float* sjp = sj2 + jbase;   // wave-uniform
    float4 o0, o1;
    o0.x = acc0[0] + acc1[0] + si + sjp[0];
    o0.y = acc0[1] + acc1[1] + si + sjp[1];
    o0.z = acc0[2] + acc1[2] + si + sjp[2];
    o0.w = acc0[3] + acc1[3] + si + sjp[3];
    o1.x = acc0[4] + acc1[4] + si + sjp[4];
    o1.y = acc0[5] + acc1[5] + si + sjp[5];
    o1.z = acc0[6] + acc1[6] + si + sjp[6];
    o1.w = acc0[7] + acc1[7] + si + sjp[7];

    float* op = out + (size_t)(rowg + lane) * SDIM + jg * 32 + w * 8;
    reinterpret_cast<float4*>(op)[0] = o0;
    reinterpret_cast<float4*>(op)[1] = o1;
}

extern "C" void kernel_launch(void* const* d_in, const int* in_sizes, int n_in,
                              void* d_out, int out_size, void* d_ws, size_t ws_size,
                              hipStream_t stream) {
    const float* x  = (const float*)d_in[0];
    const float* W1 = (const float*)d_in[1];
    const float* b1 = (const float*)d_in[2];
    const float* W2 = (const float*)d_in[3];
    const float* b2 = (const float*)d_in[4];
    float* out = (float*)d_out;

    float* ws  = (float*)d_ws;
    float* hi  = ws;                                    // B*S*D
    float* hjb = ws + (size_t)BB * SDIM * DDIM;         // B*S*D
    float* si2 = ws + (size_t)2 * BB * SDIM * DDIM;     // B*S
    float* sj2 = si2 + (size_t)BB * SDIM;               // B*S
    float* w2h = sj2 + (size_t)BB * SDIM;               // D

    proj_kernel<<<BB * SDIM / K1_ROWS, 256, 0, stream>>>(x, W1, b1, W2, b2, hi, hjb, si2, sj2, w2h);
    edge_kernel<<<dim3(SDIM / 32, SDIM / 64, BB), 256, 0, stream>>>(hi, hjb, si2, sj2, w2h, out);
}

// Round 7
// 28.134 us; speedup vs baseline: 5.6646x; 5.6646x over previous
//
#include <hip/hip_runtime.h>

#define BB 2
#define SDIM 1024
#define DDIM 128
#define K1_ROWS 4

#define F4GET(v,k) ((k)==0?(v).x:((k)==1?(v).y:((k)==2?(v).z:(v).w)))

typedef _Float16 h2v __attribute__((ext_vector_type(2)));
typedef _Float16 h8v __attribute__((ext_vector_type(8)));

__device__ __forceinline__ h2v habs2(h2v t) {
    unsigned u = __builtin_bit_cast(unsigned, t) & 0x7FFF7FFFu;
    return __builtin_bit_cast(h2v, u);
}

__device__ __forceinline__ float hdot2(h2v a, h2v b, float acc) {
#if __has_builtin(__builtin_amdgcn_fdot2)
    return __builtin_amdgcn_fdot2(a, b, acc, false);
#else
    acc = fmaf((float)a.x, (float)b.x, acc);
    return fmaf((float)a.y, (float)b.y, acc);
#endif
}

// ---------------- Kernel 1: projections + row dot products ----------------
// hi16/hjb16: f16 copies for the pair loop (halves edge LDS traffic).
// si2[n] = 0.5*(hi[n].w2) ; sj2[n] = 0.5*(hjb[n].w2) + b2  (f32, exact path)
__global__ __launch_bounds__(256) void proj_kernel(
    const float* __restrict__ x, const float* __restrict__ W1,
    const float* __restrict__ b1, const float* __restrict__ W2,
    const float* __restrict__ b2,
    ushort* __restrict__ hi16, ushort* __restrict__ hjb16,
    float* __restrict__ si2, float* __restrict__ sj2)
{
    __shared__ float sX[K1_ROWS][DDIM];
    __shared__ float sRed[4][K1_ROWS];
    const int tid  = threadIdx.x;
    const int d    = tid & 127;
    const int half = tid >> 7;
    const int r0   = blockIdx.x * K1_ROWS;

    if (tid < K1_ROWS * DDIM / 4) {
        reinterpret_cast<float4*>(&sX[0][0])[tid] =
            reinterpret_cast<const float4*>(x + (size_t)r0 * DDIM)[tid];
    }
    __syncthreads();

    const float* Wh = W1 + (size_t)half * DDIM * DDIM;

    float acc[K1_ROWS];
    #pragma unroll
    for (int r = 0; r < K1_ROWS; ++r) acc[r] = 0.f;

    #pragma unroll 4
    for (int k = 0; k < DDIM; k += 4) {
        float4 xv[K1_ROWS];
        #pragma unroll
        for (int r = 0; r < K1_ROWS; ++r)
            xv[r] = *reinterpret_cast<const float4*>(&sX[r][k]);
        #pragma unroll
        for (int kk = 0; kk < 4; ++kk) {
            float w = Wh[(size_t)(k + kk) * DDIM + d];
            #pragma unroll
            for (int r = 0; r < K1_ROWS; ++r)
                acc[r] = fmaf(F4GET(xv[r], kk), w, acc[r]);
        }
    }

    if (half) {
        const float bv = b1[d];
        #pragma unroll
        for (int r = 0; r < K1_ROWS; ++r) acc[r] += bv;
    }

    ushort* hout = half ? hjb16 : hi16;
    #pragma unroll
    for (int r = 0; r < K1_ROWS; ++r) {
        _Float16 hv = (_Float16)acc[r];
        hout[(size_t)(r0 + r) * DDIM + d] = __builtin_bit_cast(ushort, hv);
    }

    const float wv = W2[d];
    const int lane = tid & 63;
    const int wave = tid >> 6;
    #pragma unroll
    for (int r = 0; r < K1_ROWS; ++r) {
        float v = acc[r] * wv;
        #pragma unroll
        for (int off = 32; off >= 1; off >>= 1)
            v += __shfl_xor(v, off, 64);
        if (lane == 0) sRed[wave][r] = v;
    }
    __syncthreads();
    if (tid < K1_ROWS) {
        si2[r0 + tid] = 0.5f * (sRed[0][tid] + sRed[1][tid]);
    } else if (tid < 2 * K1_ROWS) {
        int r = tid - K1_ROWS;
        sj2[r0 + r] = 0.5f * (sRed[2][r] + sRed[3][r]) + b2[0];
    }
}

// ---------------- Kernel 2: pairwise edge logits (f16 tiles) ----------------
// out[b,i,j] = si2[b,i] + sj2[b,j] + sum_d |hi[b,i,d]+hjb[b,j,d]| * 0.5*w2[d]
// R4 structure (proven no-spill): 64x64 tile, 256 thr, 4x4/thread, 1 barrier.
// f16 LDS tiles: one ds_read_b128 = 8 d-slots -> LDS instrs halved vs fp32.
// Compute: v_pk_add_f16 + packed-abs(and-mask) + v_dot2_f32_f16 (f32 accum).
// Swizzles: A by (row&7) -> rows {r,8+r} share banks = 2-way (free);
//           B by (tx&7)  -> rows {4tx+c} pairwise 2-way (free).
__global__ __launch_bounds__(256) void edge_kernel(
    const ushort* __restrict__ hi16, const ushort* __restrict__ hjb16,
    const float* __restrict__ si2, const float* __restrict__ sj2,
    const float* __restrict__ W2, float* __restrict__ out)
{
    __shared__ ushort sHi[64 * DDIM];   // 16 KB, chunk-swizzled
    __shared__ ushort sHj[64 * DDIM];   // 16 KB
    __shared__ ushort sWh[DDIM];
    __shared__ float  sSi[64];
    __shared__ float  sSj[64];

    const int b   = blockIdx.z;
    const int i0  = blockIdx.y * 64;
    const int j0  = blockIdx.x * 64;
    const int tid = threadIdx.x;

    // Stage: global f16x8 -> swizzled LDS (64 rows x 16 chunks each tile).
    {
        const h8v* srcI = reinterpret_cast<const h8v*>(hi16  + ((size_t)b * SDIM + i0) * DDIM);
        const h8v* srcJ = reinterpret_cast<const h8v*>(hjb16 + ((size_t)b * SDIM + j0) * DDIM);
        h8v* dI = reinterpret_cast<h8v*>(sHi);
        h8v* dJ = reinterpret_cast<h8v*>(sHj);
        #pragma unroll
        for (int p = 0; p < 4; ++p) {
            int idx = p * 256 + tid;          // 0..1023
            int row = idx >> 4, ch = idx & 15;
            dI[row * 16 + (ch ^ (row & 7))]        = srcI[idx];
            dJ[row * 16 + (ch ^ ((row >> 2) & 7))] = srcJ[idx];
        }
    }
    if (tid < DDIM) {
        _Float16 wv = (_Float16)(0.5f * W2[tid]);
        sWh[tid] = __builtin_bit_cast(ushort, wv);
    } else if (tid < DDIM + 64) {
        sSi[tid - DDIM] = si2[b * SDIM + i0 + (tid - DDIM)];
    } else {
        sSj[tid - DDIM - 64] = sj2[b * SDIM + j0 + (tid - DDIM - 64)];
    }
    __syncthreads();

    const int tx = tid & 15;    // j sub-block: cols tx*4 .. tx*4+3
    const int ty = tid >> 4;    // i sub-block: rows ty*4 .. ty*4+3
    const int ri = ty * 4;
    const int cj = tx * 4;
    const int bswz = tx & 7;    // shared B swizzle term for all 4 B rows

    float acc[4][4];
    #pragma unroll
    for (int r = 0; r < 4; ++r)
        #pragma unroll
        for (int c = 0; c < 4; ++c) acc[r][c] = 0.f;

    const h8v* sAi = reinterpret_cast<const h8v*>(sHi);
    const h8v* sBj = reinterpret_cast<const h8v*>(sHj);
    const h8v* sWv = reinterpret_cast<const h8v*>(sWh);

    #pragma unroll 2
    for (int ch = 0; ch < 16; ++ch) {
        h8v A[4], Bv[4];
        #pragma unroll
        for (int r = 0; r < 4; ++r)
            A[r] = sAi[(ri + r) * 16 + (ch ^ ((ri + r) & 7))];
        #pragma unroll
        for (int c = 0; c < 4; ++c)
            Bv[c] = sBj[(cj + c) * 16 + (ch ^ bswz)];
        const h8v Wv = sWv[ch];   // wave-uniform addr -> broadcast (free)

        #pragma unroll
        for (int r = 0; r < 4; ++r) {
            const h2v* ap = reinterpret_cast<const h2v*>(&A[r]);
            #pragma unroll
            for (int c = 0; c < 4; ++c) {
                const h2v* bp = reinterpret_cast<const h2v*>(&Bv[c]);
                const h2v* wp = reinterpret_cast<const h2v*>(&Wv);
                float a = acc[r][c];
                #pragma unroll
                for (int k = 0; k < 4; ++k) {
                    h2v t = ap[k] + bp[k];        // v_pk_add_f16
                    a = hdot2(habs2(t), wp[k], a); // v_and + v_dot2_f32_f16
                }
                acc[r][c] = a;
            }
        }
    }

    // Epilogue: 4 consecutive j per thread -> float4 store (coalesced).
    #pragma unroll
    for (int r = 0; r < 4; ++r) {
        const float sv = sSi[ri + r];
        float4 o;
        o.x = acc[r][0] + sv + sSj[cj + 0];
        o.y = acc[r][1] + sv + sSj[cj + 1];
        o.z = acc[r][2] + sv + sSj[cj + 2];
        o.w = acc[r][3] + sv + sSj[cj + 3];
        size_t base = (size_t)b * SDIM * SDIM + (size_t)(i0 + ri + r) * SDIM + j0 + cj;
        *reinterpret_cast<float4*>(out + base) = o;
    }
}

extern "C" void kernel_launch(void* const* d_in, const int* in_sizes, int n_in,
                              void* d_out, int out_size, void* d_ws, size_t ws_size,
                              hipStream_t stream) {
    const float* x  = (const float*)d_in[0];
    const float* W1 = (const float*)d_in[1];
    const float* b1 = (const float*)d_in[2];
    const float* W2 = (const float*)d_in[3];
    const float* b2 = (const float*)d_in[4];
    float* out = (float*)d_out;

    char* ws = (char*)d_ws;
    ushort* hi16  = (ushort*)ws;                                   // B*S*D f16
    ushort* hjb16 = hi16 + (size_t)BB * SDIM * DDIM;               // B*S*D f16
    float*  si2   = (float*)(hjb16 + (size_t)BB * SDIM * DDIM);    // B*S f32
    float*  sj2   = si2 + (size_t)BB * SDIM;                       // B*S f32

    proj_kernel<<<BB * SDIM / K1_ROWS, 256, 0, stream>>>(x, W1, b1, W2, b2, hi16, hjb16, si2, sj2);
    edge_kernel<<<dim3(SDIM / 64, SDIM / 64, BB), 256, 0, stream>>>(hi16, hjb16, si2, sj2, W2, out);
}